// Round 2
// baseline (4208.625 us; speedup 1.0000x reference)
//
#include <hip/hip_runtime.h>
#include <hip/hip_bf16.h>
#include <cstdint>
#include <cstddef>

typedef unsigned int uint;
typedef unsigned short ushort;

#define BATCH 256
#define SEQT  2048
#define FIN   32
#define HID   64
#define FH    64
#define NTOT  (BATCH*SEQT)

// ---------------- ws float32 layout ----------------
enum : int {
  O_WIH0 = 0,                      // 256x32
  O_WHH0 = O_WIH0 + 256*32,        // 256x64
  O_WIH1 = O_WHH0 + 256*64,        // 256x64
  O_WHH1 = O_WIH1 + 256*64,        // 256x64
  O_B0   = O_WHH1 + 256*64,        // 256 (bih0+bhh0)
  O_B1   = O_B0 + 256,             // 256
  O_OW1  = O_B1 + 256,             // 64x9
  O_OB1  = O_OW1 + 64*9,
  O_OW2  = O_OB1 + 64,             // 64x64
  O_OB2  = O_OW2 + 64*64,
  O_OW3  = O_OB2 + 64,             // 8x64
  O_OB3  = O_OW3 + 8*64,
  O_OH0  = O_OB3 + 8,              // 8
  O_FW1  = O_OH0 + 8,              // 64x73
  O_FB1  = O_FW1 + 64*73,
  O_FW2  = O_FB1 + 64,             // 64x64
  O_FB2  = O_FW2 + 64*64,
  O_RW1  = O_FB2 + 64,             // 32x64
  O_RB1  = O_RW1 + 32*64,
  O_RW2  = O_RB1 + 32,             // 32
  O_RB2  = O_RW2 + 32,             // 1
  O_HW   = O_RB2 + 1,              // 8
  O_HB   = O_HW + 8,               // 1
  O_TRAJ = O_HB + 1,               // 366x8
  WS_F32_END = O_TRAJ + 366*8      // ~308 KB
};

#define O_FLAG_BYTE  (500*1024)
#define ENV_BYTE_OFF (512*1024)

// ---------------- helpers ----------------
__device__ __forceinline__ float blo(uint u){ return __uint_as_float(u<<16); }
__device__ __forceinline__ float bhi(uint u){ return __uint_as_float(u & 0xffff0000u); }
__device__ __forceinline__ ushort f2b(float x){      // RNE f32 -> bf16
  uint u = __float_as_uint(x);
  uint r = u + 0x7fffu + ((u>>16)&1u);
  return (ushort)(r>>16);
}
__device__ __forceinline__ float sigm(float x){ return 1.0f/(1.0f+__expf(-x)); }
__device__ __forceinline__ float tanh_fast(float x){
  x = fminf(10.0f, fmaxf(-10.0f, x));
  float e = __expf(-2.0f*x);
  return (1.0f - e)/(1.0f + e);
}
__device__ __forceinline__ void wsync(){
  __builtin_amdgcn_wave_barrier();
  __threadfence_block();
  __builtin_amdgcn_wave_barrier();
}

// ---------------- dtype detector ----------------
// f32 N(0,1) data: f32-view exponent field in [97,157] (~always).
// bf16-packed data: f32-view exponent = ((e_bf16&0x7F)<<1)|m6 -> >=200 or ~0.
__global__ void detect_kernel(const uint* __restrict__ X, int* __restrict__ flagp) {
  if (threadIdx.x == 0) {
    int cnt = 0;
    for (int i=0;i<512;i++){
      uint e = (X[i]>>23)&0xFFu;
      cnt += (e>=97u && e<=157u) ? 1 : 0;
    }
    *flagp = (cnt >= 300) ? 1 : 0;   // 1 = float32 inputs, 0 = bf16 inputs
  }
}

// ---------------- prep: weights -> f32 in ws ----------------
struct Ptrs { const void* p[28]; };

__global__ void prep_kernel(Ptrs ptrs, float* __restrict__ ws, const int* __restrict__ flagp) {
  const int flag = *flagp;
  const int tid = blockIdx.x*blockDim.x + threadIdx.x;
  const int nth = gridDim.x*blockDim.x;
  auto cv = [&](int dst, int srcidx, int n){
    if (flag) {
      const float* s = (const float*)ptrs.p[srcidx];
      for (int i=tid;i<n;i+=nth) ws[dst+i] = s[i];
    } else {
      const ushort* s = (const ushort*)ptrs.p[srcidx];
      for (int i=tid;i<n;i+=nth) ws[dst+i] = __uint_as_float(((uint)s[i])<<16);
    }
  };
  auto rd = [&](int srcidx, int i)->float{
    if (flag) return ((const float*)ptrs.p[srcidx])[i];
    return __uint_as_float(((uint)((const ushort*)ptrs.p[srcidx])[i])<<16);
  };
  cv(O_WIH0,10,8192); cv(O_WHH0,11,16384); cv(O_WIH1,14,16384); cv(O_WHH1,15,16384);
  for (int i=tid;i<256;i+=nth) ws[O_B0+i] = rd(12,i) + rd(13,i);
  for (int i=tid;i<256;i+=nth) ws[O_B1+i] = rd(16,i) + rd(17,i);
  cv(O_OW1,4,576); cv(O_OB1,5,64); cv(O_OW2,6,4096); cv(O_OB2,7,64);
  cv(O_OW3,8,512); cv(O_OB3,9,8);  cv(O_OH0,3,8);
  cv(O_FW1,20,4672); cv(O_FB1,21,64); cv(O_FW2,22,4096); cv(O_FB2,23,64);
  cv(O_RW1,24,2048); cv(O_RB1,25,32); cv(O_RW2,26,32); cv(O_RB2,27,1);
  cv(O_HW,18,8); cv(O_HB,19,1);
}

// ---------------- ODE (single wave 0, lockstep + fences) ----------------
__device__ void ode_wave(float* __restrict__ ws, float* sbuf) {
  const int lane = threadIdx.x;     // 0..63
  float* sZ1 = sbuf;
  float* sZ2 = sbuf + 64;
  float* sK  = sbuf + 128;

  float w1[9];
#pragma unroll
  for (int k=0;k<9;k++) w1[k]=ws[O_OW1+lane*9+k];
  const float b1 = ws[O_OB1+lane];
  float w2[64];
#pragma unroll
  for (int k=0;k<64;k++) w2[k]=ws[O_OW2+lane*64+k];
  const float b2 = ws[O_OB2+lane];
  const int m = lane>>3, s = lane&7;
  float w3[8];
#pragma unroll
  for (int k=0;k<8;k++) w3[k]=ws[O_OW3+m*64+s*8+k];
  const float b3m = ws[O_OB3+m];

  float h[8];
#pragma unroll
  for (int k=0;k<8;k++) h[k]=ws[O_OH0+k];

  {
    float sel = h[0];
#pragma unroll
    for (int i=1;i<8;i++) sel = (lane==i)? h[i] : sel;
    if (lane<8) ws[O_TRAJ+lane]=sel;
  }

  const float dt = 1.0f/365.0f;
  float k1[8],k2[8],k3[8],k4[8],k5[8],k6[8],ht[8];

  auto feval = [&](const float* hin, float te, float* kout) {
    float a = b1;
#pragma unroll
    for (int k=0;k<8;k++) a += w1[k]*hin[k];
    a += w1[8]*te;
    sZ1[lane] = tanh_fast(a);
    wsync();
    float acc = b2;
    {
      const float4* z4 = (const float4*)sZ1;
#pragma unroll
      for (int k=0;k<16;k++){ float4 v=z4[k];
        acc += w2[4*k]*v.x + w2[4*k+1]*v.y + w2[4*k+2]*v.z + w2[4*k+3]*v.w; }
    }
    sZ2[lane] = tanh_fast(acc);
    wsync();
    float part;
    {
      const float4* q = (const float4*)(sZ2 + s*8);
      float4 p0=q[0], p1=q[1];
      part = w3[0]*p0.x + w3[1]*p0.y + w3[2]*p0.z + w3[3]*p0.w
           + w3[4]*p1.x + w3[5]*p1.y + w3[6]*p1.z + w3[7]*p1.w;
    }
    part += __shfl_xor(part, 1);
    part += __shfl_xor(part, 2);
    part += __shfl_xor(part, 4);
    if (s==0) sK[m] = part + b3m;
    wsync();
    {
      const float4* kk = (const float4*)sK;
      float4 a0=kk[0], a1=kk[1];
      kout[0]=a0.x; kout[1]=a0.y; kout[2]=a0.z; kout[3]=a0.w;
      kout[4]=a1.x; kout[5]=a1.y; kout[6]=a1.z; kout[7]=a1.w;
    }
    wsync();
  };

  for (int d=0; d<365; d++) {
    float t0 = (float)d * dt;
    feval(h, t0, k1);
#pragma unroll
    for (int i=0;i<8;i++) ht[i] = h[i] + dt*(0.2f*k1[i]);
    feval(ht, t0 + 0.2f*dt, k2);
#pragma unroll
    for (int i=0;i<8;i++) ht[i] = h[i] + dt*((3.0f/40.0f)*k1[i] + (9.0f/40.0f)*k2[i]);
    feval(ht, t0 + 0.3f*dt, k3);
#pragma unroll
    for (int i=0;i<8;i++) ht[i] = h[i] + dt*((44.0f/45.0f)*k1[i] - (56.0f/15.0f)*k2[i] + (32.0f/9.0f)*k3[i]);
    feval(ht, t0 + 0.8f*dt, k4);
#pragma unroll
    for (int i=0;i<8;i++) ht[i] = h[i] + dt*((19372.0f/6561.0f)*k1[i] - (25360.0f/2187.0f)*k2[i]
                                   + (64448.0f/6561.0f)*k3[i] - (212.0f/729.0f)*k4[i]);
    feval(ht, t0 + (8.0f/9.0f)*dt, k5);
#pragma unroll
    for (int i=0;i<8;i++) ht[i] = h[i] + dt*((9017.0f/3168.0f)*k1[i] - (355.0f/33.0f)*k2[i]
                                   + (46732.0f/5247.0f)*k3[i] + (49.0f/176.0f)*k4[i]
                                   - (5103.0f/18656.0f)*k5[i]);
    feval(ht, t0 + dt, k6);
#pragma unroll
    for (int i=0;i<8;i++) h[i] += dt*((35.0f/384.0f)*k1[i] + (500.0f/1113.0f)*k3[i]
                                   + (125.0f/192.0f)*k4[i] - (2187.0f/6784.0f)*k5[i]
                                   + (11.0f/84.0f)*k6[i]);
    float sel = h[0];
#pragma unroll
    for (int i=1;i<8;i++) sel = (lane==i)? h[i] : sel;
    if (lane<8) ws[O_TRAJ + (d+1)*8 + lane] = sel;
  }
}

// ---------------- LSTM (1 block per sample) + ODE block ----------------
#define XCHUNK 128

__global__ __launch_bounds__(256, 2) void lstm_ode_kernel(const void* __restrict__ Xv,
                                                          float* __restrict__ ws,
                                                          ushort* __restrict__ env,
                                                          const int* __restrict__ flagp,
                                                          int b0, int runOde, int nb) {
  __shared__ __align__(16) float sx[XCHUNK*FIN];   // 16 KB x-chunk (f32)
  __shared__ __align__(16) float sh1[HID];
  __shared__ __align__(16) float sh2[HID];
  __shared__ __align__(16) float sgA[4*HID];
  __shared__ __align__(16) float sgB[4*HID];

  if ((int)blockIdx.x == nb) {        // dedicated ODE block (slice 0 only)
    if (runOde && threadIdx.x < 64) ode_wave(ws, sx);
    return;
  }

  const int flag = *flagp;
  const int b = b0 + blockIdx.x;      // global sample
  const int j = threadIdx.x;

  // per-thread gate-row weights in VGPRs (224 f32)
  float wih0[FIN], whh0[HID], wih1[HID], whh1[HID];
  {
    const float4* p = (const float4*)(ws + O_WIH0) + j*(FIN/4);
#pragma unroll
    for (int k=0;k<FIN/4;k++){ float4 v=p[k]; wih0[4*k]=v.x; wih0[4*k+1]=v.y; wih0[4*k+2]=v.z; wih0[4*k+3]=v.w; }
  }
  {
    const float4* p = (const float4*)(ws + O_WHH0) + j*(HID/4);
#pragma unroll
    for (int k=0;k<HID/4;k++){ float4 v=p[k]; whh0[4*k]=v.x; whh0[4*k+1]=v.y; whh0[4*k+2]=v.z; whh0[4*k+3]=v.w; }
  }
  {
    const float4* p = (const float4*)(ws + O_WIH1) + j*(HID/4);
#pragma unroll
    for (int k=0;k<HID/4;k++){ float4 v=p[k]; wih1[4*k]=v.x; wih1[4*k+1]=v.y; wih1[4*k+2]=v.z; wih1[4*k+3]=v.w; }
  }
  {
    const float4* p = (const float4*)(ws + O_WHH1) + j*(HID/4);
#pragma unroll
    for (int k=0;k<HID/4;k++){ float4 v=p[k]; whh1[4*k]=v.x; whh1[4*k+1]=v.y; whh1[4*k+2]=v.z; whh1[4*k+3]=v.w; }
  }
  const float bias0 = ws[O_B0+j];
  const float bias1 = ws[O_B1+j];
  float cst = 0.0f;                   // c1 for j<64, c2 for 64<=j<128
  if (j < HID) { sh1[j]=0.0f; sh2[j]=0.0f; }
  const uint*   xrow_b = (const uint*)Xv   + (size_t)b*SEQT*(FIN/2);
  const float4* xrow_f = (const float4*)((const float*)Xv + (size_t)b*SEQT*FIN);
  ushort* erow = env + (size_t)blockIdx.x*SEQT*HID;   // slice-local row
  __syncthreads();

  for (int t0=0; t0<SEQT; t0+=XCHUNK) {
    if (flag) {                       // float32 input
      const float4* xc = xrow_f + t0*(FIN/4);
#pragma unroll
      for (int it=0; it<(XCHUNK*FIN/4)/256; it++) {   // 4
        int idx = it*256 + j;
        ((float4*)sx)[idx] = xc[idx];
      }
    } else {                          // bf16 input
      const uint* xc = xrow_b + t0*(FIN/2);
#pragma unroll
      for (int it=0; it<(XCHUNK*FIN/2)/256; it++) {   // 8
        int idx = it*256 + j;
        uint u = xc[idx];
        sx[2*idx]   = blo(u);
        sx[2*idx+1] = bhi(u);
      }
    }
    __syncthreads();
    for (int tt=0; tt<XCHUNK; tt++) {
      // P1: layer-0 gates
      float acc = bias0;
      {
        const float4* xr = (const float4*)(sx + tt*FIN);
#pragma unroll
        for (int k=0;k<FIN/4;k++){ float4 v=xr[k];
          acc += wih0[4*k]*v.x + wih0[4*k+1]*v.y + wih0[4*k+2]*v.z + wih0[4*k+3]*v.w; }
        const float4* hr = (const float4*)sh1;
#pragma unroll
        for (int k=0;k<HID/4;k++){ float4 v=hr[k];
          acc += whh0[4*k]*v.x + whh0[4*k+1]*v.y + whh0[4*k+2]*v.z + whh0[4*k+3]*v.w; }
      }
      sgA[j] = acc;
      __syncthreads();                              // #1
      // P2: layer-0 cell update (wave 0)
      if (j < HID) {
        float gi=sgA[j], gf=sgA[HID+j], gg=sgA[2*HID+j], go=sgA[3*HID+j];
        cst = sigm(gf)*cst + sigm(gi)*tanh_fast(gg);
        sh1[j] = sigm(go)*tanh_fast(cst);
      }
      __syncthreads();                              // #2
      // P3: layer-1 gates
      float acc2 = bias1;
      {
        const float4* hr = (const float4*)sh1;
#pragma unroll
        for (int k=0;k<HID/4;k++){ float4 v=hr[k];
          acc2 += wih1[4*k]*v.x + wih1[4*k+1]*v.y + wih1[4*k+2]*v.z + wih1[4*k+3]*v.w; }
        const float4* h2r = (const float4*)sh2;
#pragma unroll
        for (int k=0;k<HID/4;k++){ float4 v=h2r[k];
          acc2 += whh1[4*k]*v.x + whh1[4*k+1]*v.y + whh1[4*k+2]*v.z + whh1[4*k+3]*v.w; }
      }
      sgB[j] = acc2;
      __syncthreads();                              // #3
      // P4: layer-1 cell update (wave 1) + env store
      if (j >= HID && j < 2*HID) {
        int u = j - HID;
        float gi=sgB[u], gf=sgB[HID+u], gg=sgB[2*HID+u], go=sgB[3*HID+u];
        cst = sigm(gf)*cst + sigm(gi)*tanh_fast(gg);
        float h2 = sigm(go)*tanh_fast(cst);
        sh2[u] = h2;
        erow[(size_t)(t0+tt)*HID + u] = f2b(h2);
      }
    }
  }
}

// ---------------- fusion MLP + outputs ----------------
__global__ __launch_bounds__(256) void fuse_kernel(const ushort* __restrict__ envb,
                                                   const float* __restrict__ ws,
                                                   const int* __restrict__ day_ids,
                                                   const void* __restrict__ rawv,
                                                   void* __restrict__ outv,
                                                   const int* __restrict__ flagp,
                                                   int b0, int nb) {
  const int flag = *flagp;
  const int eloc = blockIdx.x*256 + threadIdx.x;     // slice-local element
  const int bloc = eloc >> 11;
  const int b = b0 + bloc;                           // global sample
  const size_t ge = (size_t)b*SEQT + (eloc & 2047);  // global element

  int day = day_ids[b];
  day = day < 0 ? 0 : (day > 365 ? 365 : day);
  float hl[8];
#pragma unroll
  for (int i=0;i<8;i++) hl[i] = ws[O_TRAJ + day*8 + i];
  float rawD = ws[O_HB];
#pragma unroll
  for (int i=0;i<8;i++) rawD += hl[i]*ws[O_HW+i];
  const float Dv = sigm(rawD);

  float z[HID];
  {
    const uint4* ev = (const uint4*)(envb + (size_t)eloc*HID);
#pragma unroll
    for (int q=0;q<8;q++){
      uint4 u = ev[q];
      z[8*q+0]=blo(u.x); z[8*q+1]=bhi(u.x);
      z[8*q+2]=blo(u.y); z[8*q+3]=bhi(u.y);
      z[8*q+4]=blo(u.z); z[8*q+5]=bhi(u.z);
      z[8*q+6]=blo(u.w); z[8*q+7]=bhi(u.w);
    }
  }
  float G, Tc;
  if (flag) {
    float2 fr = ((const float2*)rawv)[ge*2];         // raw row = 4 f32 = 2 float2
    G = fr.x; Tc = fr.y;
  } else {
    uint gr = ((const uint*)rawv)[ge*2];             // raw row = 4 bf16 = 2 uint
    G = blo(gr); Tc = bhi(gr);
  }
  const float Ip = G*9.0f*(1.0f + 0.0005f*(Tc-0.5f));

  float f1[FH];
#pragma unroll
  for (int jj=0;jj<FH;jj++){
    const float* wr = ws + O_FW1 + jj*73;
    float a = ws[O_FB1+jj];
#pragma unroll
    for (int k=0;k<HID;k++) a += wr[k]*z[k];
#pragma unroll
    for (int i=0;i<8;i++) a += wr[HID+i]*hl[i];
    a += wr[72]*Ip;
    f1[jj] = fmaxf(a,0.0f);
  }
  float f2[FH];
#pragma unroll
  for (int jj=0;jj<FH;jj++){
    const float* wr = ws + O_FW2 + jj*FH;
    float a = ws[O_FB2+jj];
#pragma unroll
    for (int k=0;k<FH;k++) a += wr[k]*f1[k];
    f2[jj] = fmaxf(a,0.0f);
  }
  float racc = ws[O_RB2];
#pragma unroll
  for (int mm=0;mm<32;mm++){
    const float* wr = ws + O_RW1 + mm*FH;
    float a = ws[O_RB1+mm];
#pragma unroll
    for (int k=0;k<FH;k++) a += wr[k]*f2[k];
    racc += ws[O_RW2+mm]*fmaxf(a,0.0f);
  }
  const float Ib = Dv*Ip;
  const float Ipred = Ib + racc;

  if (flag) {                                        // float32 outputs
    float* o = (float*)outv;
    o[ge] = Ipred; o[NTOT+ge] = Ip; o[(size_t)2*NTOT+ge] = Ib;
    o[(size_t)3*NTOT+ge] = Dv; o[(size_t)4*NTOT+ge] = racc;
    float4* hp = (float4*)(o + (size_t)5*NTOT + ge*8);
    hp[0] = make_float4(hl[0],hl[1],hl[2],hl[3]);
    hp[1] = make_float4(hl[4],hl[5],hl[6],hl[7]);
  } else {                                           // bf16 outputs
    ushort* o = (ushort*)outv;
    o[ge] = f2b(Ipred); o[NTOT+ge] = f2b(Ip); o[(size_t)2*NTOT+ge] = f2b(Ib);
    o[(size_t)3*NTOT+ge] = f2b(Dv); o[(size_t)4*NTOT+ge] = f2b(racc);
    uint4 hsv;
    hsv.x = (uint)f2b(hl[0]) | ((uint)f2b(hl[1])<<16);
    hsv.y = (uint)f2b(hl[2]) | ((uint)f2b(hl[3])<<16);
    hsv.z = (uint)f2b(hl[4]) | ((uint)f2b(hl[5])<<16);
    hsv.w = (uint)f2b(hl[6]) | ((uint)f2b(hl[7])<<16);
    *((uint4*)(o + (size_t)5*NTOT + ge*8)) = hsv;
  }
}

// ---------------- launch ----------------
extern "C" void kernel_launch(void* const* d_in, const int* in_sizes, int n_in,
                              void* d_out, int out_size, void* d_ws, size_t ws_size,
                              hipStream_t stream) {
  (void)in_sizes; (void)out_size;
  float* wsf = (float*)d_ws;
  int* flagp = (int*)((char*)d_ws + O_FLAG_BYTE);
  ushort* env = (ushort*)((char*)d_ws + ENV_BYTE_OFF);
  Ptrs pa;
  for (int i=0;i<28;i++) pa.p[i] = (i<n_in) ? d_in[i] : d_in[0];

  // batch slicing so env fits in ws (env slice = nb*SEQT*HID*2 bytes)
  int S = 1;
  while (S < 128) {
    size_t need = (size_t)ENV_BYTE_OFF + (size_t)(BATCH/S)*SEQT*HID*2;
    if (need <= ws_size) break;
    S <<= 1;
  }
  const int nb = BATCH / S;

  detect_kernel<<<1, 64, 0, stream>>>((const uint*)d_in[0], flagp);
  prep_kernel<<<128, 256, 0, stream>>>(pa, wsf, flagp);
  for (int s=0; s<S; s++) {
    lstm_ode_kernel<<<nb+1, 256, 0, stream>>>(d_in[0], wsf, env, flagp,
                                              s*nb, (s==0)?1:0, nb);
    fuse_kernel<<<nb*(SEQT/256), 256, 0, stream>>>(env, wsf, (const int*)d_in[1],
                                                   d_in[2], d_out, flagp, s*nb, nb);
  }
}

// Round 3
// 2690.936 us; speedup vs baseline: 1.5640x; 1.5640x over previous
//
#include <hip/hip_runtime.h>
#include <hip/hip_bf16.h>
#include <cstdint>
#include <cstddef>

typedef unsigned int uint;
typedef unsigned short ushort;
typedef _Float16 half2_t __attribute__((ext_vector_type(2)));

#define BATCH 256
#define SEQT  2048
#define FIN   32
#define HID   64
#define FH    64
#define NTOT  (BATCH*SEQT)

// ---------------- ws layout (f32 words) ----------------
enum : int {
  O_B0   = 0,                      // 256 (bih0+bhh0)
  O_B1   = O_B0 + 256,             // 256
  O_OW1  = O_B1 + 256,             // 64x9
  O_OB1  = O_OW1 + 64*9,
  O_OW2  = O_OB1 + 64,             // 64x64
  O_OB2  = O_OW2 + 64*64,
  O_OW3  = O_OB2 + 64,             // 8x64
  O_OB3  = O_OW3 + 8*64,
  O_OH0  = O_OB3 + 8,              // 8
  O_FW1  = O_OH0 + 8,              // 64x73
  O_FB1  = O_FW1 + 64*73,
  O_FW2  = O_FB1 + 64,             // 64x64
  O_FB2  = O_FW2 + 64*64,
  O_RW1  = O_FB2 + 64,             // 32x64
  O_RB1  = O_RW1 + 32*64,
  O_RW2  = O_RB1 + 32,             // 32
  O_RB2  = O_RW2 + 32,             // 1
  O_HW   = O_RB2 + 1,              // 8
  O_HB   = O_HW + 8,               // 1
  O_TRAJ = O_HB + 1,               // 366x8
  WS_F32_END = O_TRAJ + 366*8,
  // packed-f16 LSTM weights (1 uint = 2 f16), word offsets
  H_WIH0 = WS_F32_END,             // 256x16 uints
  H_WHH0 = H_WIH0 + 256*16,        // 256x32
  H_WIH1 = H_WHH0 + 256*32,        // 256x32
  H_WHH1 = H_WIH1 + 256*32,        // 256x32
  WS_END2 = H_WHH1 + 256*32        // ~423 KB
};

#define O_FLAG_BYTE  (500*1024)
#define ENV_BYTE_OFF (512*1024)

// ---------------- helpers ----------------
__device__ __forceinline__ float blo(uint u){ return __uint_as_float(u<<16); }
__device__ __forceinline__ float bhi(uint u){ return __uint_as_float(u & 0xffff0000u); }
__device__ __forceinline__ ushort f2b(float x){      // RNE f32 -> bf16
  uint u = __float_as_uint(x);
  uint r = u + 0x7fffu + ((u>>16)&1u);
  return (ushort)(r>>16);
}
__device__ __forceinline__ float sigm(float x){ return 1.0f/(1.0f+__expf(-x)); }
__device__ __forceinline__ float tanh_fast(float x){
  x = fminf(10.0f, fmaxf(-10.0f, x));
  float e = __expf(-2.0f*x);
  return (1.0f - e)/(1.0f + e);
}
__device__ __forceinline__ void wsync(){
  __builtin_amdgcn_wave_barrier();
  __threadfence_block();
  __builtin_amdgcn_wave_barrier();
}
__device__ __forceinline__ uint pkh2(float a, float b){
  half2_t h; h.x=(_Float16)a; h.y=(_Float16)b;
  return __builtin_bit_cast(uint, h);
}
__device__ __forceinline__ half2_t uph(uint u){ return __builtin_bit_cast(half2_t, u); }
__device__ __forceinline__ ushort hbits(float x){ return __builtin_bit_cast(ushort, (_Float16)x); }

#if __has_builtin(__builtin_amdgcn_fdot2)
__device__ __forceinline__ float FDOT2(half2_t a, half2_t b, float c){
  return __builtin_amdgcn_fdot2(a, b, c, false);
}
#else
__device__ __forceinline__ float FDOT2(half2_t a, half2_t b, float c){
  return c + (float)a.x*(float)b.x + (float)a.y*(float)b.y;
}
#endif

// ---------------- dtype detector ----------------
__global__ void detect_kernel(const uint* __restrict__ X, int* __restrict__ flagp) {
  if (threadIdx.x == 0) {
    int cnt = 0;
    for (int i=0;i<512;i++){
      uint e = (X[i]>>23)&0xFFu;
      cnt += (e>=97u && e<=157u) ? 1 : 0;
    }
    *flagp = (cnt >= 300) ? 1 : 0;   // 1 = float32 inputs, 0 = bf16 inputs
  }
}

// ---------------- prep ----------------
struct Ptrs { const void* p[28]; };

__global__ void prep_kernel(Ptrs ptrs, float* __restrict__ ws, const int* __restrict__ flagp) {
  const int flag = *flagp;
  const int tid = blockIdx.x*blockDim.x + threadIdx.x;
  const int nth = gridDim.x*blockDim.x;
  auto cv = [&](int dst, int srcidx, int n){
    if (flag) {
      const float* s = (const float*)ptrs.p[srcidx];
      for (int i=tid;i<n;i+=nth) ws[dst+i] = s[i];
    } else {
      const ushort* s = (const ushort*)ptrs.p[srcidx];
      for (int i=tid;i<n;i+=nth) ws[dst+i] = __uint_as_float(((uint)s[i])<<16);
    }
  };
  auto rd = [&](int srcidx, int i)->float{
    if (flag) return ((const float*)ptrs.p[srcidx])[i];
    return __uint_as_float(((uint)((const ushort*)ptrs.p[srcidx])[i])<<16);
  };
  // packed-f16 LSTM weights straight from source (rows have even length)
  auto cvh = [&](int dstw, int srcidx, int n2){
    uint* d = (uint*)ws;
    if (flag) {
      const float* s = (const float*)ptrs.p[srcidx];
      for (int i=tid;i<n2;i+=nth) d[dstw+i] = pkh2(s[2*i], s[2*i+1]);
    } else {
      const uint* s = (const uint*)ptrs.p[srcidx];
      for (int i=tid;i<n2;i+=nth){ uint u=s[i]; d[dstw+i] = pkh2(blo(u), bhi(u)); }
    }
  };
  cvh(H_WIH0,10,4096); cvh(H_WHH0,11,8192); cvh(H_WIH1,14,8192); cvh(H_WHH1,15,8192);
  for (int i=tid;i<256;i+=nth) ws[O_B0+i] = rd(12,i) + rd(13,i);
  for (int i=tid;i<256;i+=nth) ws[O_B1+i] = rd(16,i) + rd(17,i);
  cv(O_OW1,4,576); cv(O_OB1,5,64); cv(O_OW2,6,4096); cv(O_OB2,7,64);
  cv(O_OW3,8,512); cv(O_OB3,9,8);  cv(O_OH0,3,8);
  cv(O_FW1,20,4672); cv(O_FB1,21,64); cv(O_FW2,22,4096); cv(O_FB2,23,64);
  cv(O_RW1,24,2048); cv(O_RB1,25,32); cv(O_RW2,26,32); cv(O_RB2,27,1);
  cv(O_HW,18,8); cv(O_HB,19,1);
}

// ---------------- ODE (single wave 0, lockstep + fences) ----------------
__device__ void ode_wave(float* __restrict__ ws, float* sbuf) {
  const int lane = threadIdx.x;     // 0..63
  float* sZ1 = sbuf;
  float* sZ2 = sbuf + 64;
  float* sK  = sbuf + 128;

  float w1[9];
#pragma unroll
  for (int k=0;k<9;k++) w1[k]=ws[O_OW1+lane*9+k];
  const float b1 = ws[O_OB1+lane];
  float w2[64];
#pragma unroll
  for (int k=0;k<64;k++) w2[k]=ws[O_OW2+lane*64+k];
  const float b2 = ws[O_OB2+lane];
  const int m = lane>>3, s = lane&7;
  float w3[8];
#pragma unroll
  for (int k=0;k<8;k++) w3[k]=ws[O_OW3+m*64+s*8+k];
  const float b3m = ws[O_OB3+m];

  float h[8];
#pragma unroll
  for (int k=0;k<8;k++) h[k]=ws[O_OH0+k];

  {
    float sel = h[0];
#pragma unroll
    for (int i=1;i<8;i++) sel = (lane==i)? h[i] : sel;
    if (lane<8) ws[O_TRAJ+lane]=sel;
  }

  const float dt = 1.0f/365.0f;
  float k1[8],k2[8],k3[8],k4[8],k5[8],k6[8],ht[8];

  auto feval = [&](const float* hin, float te, float* kout) {
    float a = b1;
#pragma unroll
    for (int k=0;k<8;k++) a += w1[k]*hin[k];
    a += w1[8]*te;
    sZ1[lane] = tanh_fast(a);
    wsync();
    float acc = b2;
    {
      const float4* z4 = (const float4*)sZ1;
#pragma unroll
      for (int k=0;k<16;k++){ float4 v=z4[k];
        acc += w2[4*k]*v.x + w2[4*k+1]*v.y + w2[4*k+2]*v.z + w2[4*k+3]*v.w; }
    }
    sZ2[lane] = tanh_fast(acc);
    wsync();
    float part;
    {
      const float4* q = (const float4*)(sZ2 + s*8);
      float4 p0=q[0], p1=q[1];
      part = w3[0]*p0.x + w3[1]*p0.y + w3[2]*p0.z + w3[3]*p0.w
           + w3[4]*p1.x + w3[5]*p1.y + w3[6]*p1.z + w3[7]*p1.w;
    }
    part += __shfl_xor(part, 1);
    part += __shfl_xor(part, 2);
    part += __shfl_xor(part, 4);
    if (s==0) sK[m] = part + b3m;
    wsync();
    {
      const float4* kk = (const float4*)sK;
      float4 a0=kk[0], a1=kk[1];
      kout[0]=a0.x; kout[1]=a0.y; kout[2]=a0.z; kout[3]=a0.w;
      kout[4]=a1.x; kout[5]=a1.y; kout[6]=a1.z; kout[7]=a1.w;
    }
    wsync();
  };

  for (int d=0; d<365; d++) {
    float t0 = (float)d * dt;
    feval(h, t0, k1);
#pragma unroll
    for (int i=0;i<8;i++) ht[i] = h[i] + dt*(0.2f*k1[i]);
    feval(ht, t0 + 0.2f*dt, k2);
#pragma unroll
    for (int i=0;i<8;i++) ht[i] = h[i] + dt*((3.0f/40.0f)*k1[i] + (9.0f/40.0f)*k2[i]);
    feval(ht, t0 + 0.3f*dt, k3);
#pragma unroll
    for (int i=0;i<8;i++) ht[i] = h[i] + dt*((44.0f/45.0f)*k1[i] - (56.0f/15.0f)*k2[i] + (32.0f/9.0f)*k3[i]);
    feval(ht, t0 + 0.8f*dt, k4);
#pragma unroll
    for (int i=0;i<8;i++) ht[i] = h[i] + dt*((19372.0f/6561.0f)*k1[i] - (25360.0f/2187.0f)*k2[i]
                                   + (64448.0f/6561.0f)*k3[i] - (212.0f/729.0f)*k4[i]);
    feval(ht, t0 + (8.0f/9.0f)*dt, k5);
#pragma unroll
    for (int i=0;i<8;i++) ht[i] = h[i] + dt*((9017.0f/3168.0f)*k1[i] - (355.0f/33.0f)*k2[i]
                                   + (46732.0f/5247.0f)*k3[i] + (49.0f/176.0f)*k4[i]
                                   - (5103.0f/18656.0f)*k5[i]);
    feval(ht, t0 + dt, k6);
#pragma unroll
    for (int i=0;i<8;i++) h[i] += dt*((35.0f/384.0f)*k1[i] + (500.0f/1113.0f)*k3[i]
                                   + (125.0f/192.0f)*k4[i] - (2187.0f/6784.0f)*k5[i]
                                   + (11.0f/84.0f)*k6[i]);
    float sel = h[0];
#pragma unroll
    for (int i=1;i<8;i++) sel = (lane==i)? h[i] : sel;
    if (lane<8) ws[O_TRAJ + (d+1)*8 + lane] = sel;
  }
}

// ---------------- LSTM: layer-skewed, f16 dot2, 2 barriers/step ----------------
#define XCHUNK 128

__global__ __launch_bounds__(256, 1) void lstm_ode_kernel(const void* __restrict__ Xv,
                                                          float* __restrict__ ws,
                                                          ushort* __restrict__ env,
                                                          const int* __restrict__ flagp,
                                                          int b0, int runOde, int nb) {
  __shared__ __align__(16) uint  sxu[XCHUNK*16];   // x chunk as packed f16, 8 KB
  __shared__ __align__(16) uint  sh1u[32];         // h1 as packed f16
  __shared__ __align__(16) uint  sh2u[32];         // h2 as packed f16
  __shared__ __align__(16) float sgA[256];         // layer0 gates (t)
  __shared__ __align__(16) float sgB[256];         // layer1 gates (t-1)

  if ((int)blockIdx.x == nb) {        // dedicated ODE block (slice 0 only)
    if (runOde && threadIdx.x < 64) ode_wave(ws, (float*)sxu);
    return;
  }

  const int flag = *flagp;
  const int b = b0 + blockIdx.x;
  const int j = threadIdx.x;
  const uint* wsu = (const uint*)ws;

  // per-thread packed-f16 gate-row weights: 112 uints
  uint wx0[16], wh0[32], wh1[32], ww1[32];
  {
    const uint4* p = (const uint4*)(wsu + H_WIH0 + j*16);
#pragma unroll
    for (int q=0;q<4;q++){ uint4 v=p[q]; wx0[4*q]=v.x; wx0[4*q+1]=v.y; wx0[4*q+2]=v.z; wx0[4*q+3]=v.w; }
  }
  {
    const uint4* p = (const uint4*)(wsu + H_WHH0 + j*32);
#pragma unroll
    for (int q=0;q<8;q++){ uint4 v=p[q]; wh0[4*q]=v.x; wh0[4*q+1]=v.y; wh0[4*q+2]=v.z; wh0[4*q+3]=v.w; }
  }
  {
    const uint4* p = (const uint4*)(wsu + H_WIH1 + j*32);
#pragma unroll
    for (int q=0;q<8;q++){ uint4 v=p[q]; wh1[4*q]=v.x; wh1[4*q+1]=v.y; wh1[4*q+2]=v.z; wh1[4*q+3]=v.w; }
  }
  {
    const uint4* p = (const uint4*)(wsu + H_WHH1 + j*32);
#pragma unroll
    for (int q=0;q<8;q++){ uint4 v=p[q]; ww1[4*q]=v.x; ww1[4*q+1]=v.y; ww1[4*q+2]=v.z; ww1[4*q+3]=v.w; }
  }
  const float bias0 = ws[O_B0+j];
  const float bias1 = ws[O_B1+j];
  float cst = 0.0f;                   // c1[j] for j<64, c2[j-64] for 64<=j<128
  if (j < 32) { sh1u[j]=0u; sh2u[j]=0u; }
  const uint*   xrow_b = (const uint*)Xv + (size_t)b*SEQT*(FIN/2);
  const float2* xrow_f = (const float2*)((const float*)Xv + (size_t)b*SEQT*FIN);
  ushort* erow = env + (size_t)blockIdx.x*SEQT*HID;
  __syncthreads();

  for (int t=0; t<=SEQT; ++t) {
    if ((t & (XCHUNK-1)) == 0 && t < SEQT) {       // stage next x chunk as f16
      if (flag) {
        const float2* xc = xrow_f + t*(FIN/2);
#pragma unroll
        for (int it=0; it<(XCHUNK*16)/256; it++){  // 8
          int idx = it*256 + j;
          float2 v = xc[idx];
          sxu[idx] = pkh2(v.x, v.y);
        }
      } else {
        const uint* xc = xrow_b + t*(FIN/2);
#pragma unroll
        for (int it=0; it<(XCHUNK*16)/256; it++){  // 8
          int idx = it*256 + j;
          uint u = xc[idx];
          sxu[idx] = pkh2(blo(u), bhi(u));
        }
      }
      __syncthreads();
    }
    const int tt = t & (XCHUNK-1);

    // ---- Phase A: gates (layer0 @ t, layer1 @ t-1); h1 read once, reused
    uint h1r[32];
    {
      const uint4* p = (const uint4*)sh1u;
#pragma unroll
      for (int q=0;q<8;q++){ uint4 v=p[q]; h1r[4*q]=v.x; h1r[4*q+1]=v.y; h1r[4*q+2]=v.z; h1r[4*q+3]=v.w; }
    }
    uint h2r[32];
    {
      const uint4* p = (const uint4*)sh2u;
#pragma unroll
      for (int q=0;q<8;q++){ uint4 v=p[q]; h2r[4*q]=v.x; h2r[4*q+1]=v.y; h2r[4*q+2]=v.z; h2r[4*q+3]=v.w; }
    }
    if (t < SEQT) {
      uint xr[16];
      const uint4* p = (const uint4*)(sxu + tt*16);
#pragma unroll
      for (int q=0;q<4;q++){ uint4 v=p[q]; xr[4*q]=v.x; xr[4*q+1]=v.y; xr[4*q+2]=v.z; xr[4*q+3]=v.w; }
      float a[4] = {bias0, 0.0f, 0.0f, 0.0f};
#pragma unroll
      for (int k=0;k<16;k++) a[k&3] = FDOT2(uph(wx0[k]), uph(xr[k]), a[k&3]);
#pragma unroll
      for (int k=0;k<32;k++) a[k&3] = FDOT2(uph(wh0[k]), uph(h1r[k]), a[k&3]);
      sgA[j] = (a[0]+a[1])+(a[2]+a[3]);
    }
    if (t >= 1) {
      float c[4] = {bias1, 0.0f, 0.0f, 0.0f};
#pragma unroll
      for (int k=0;k<32;k++) c[k&3] = FDOT2(uph(wh1[k]), uph(h1r[k]), c[k&3]);
#pragma unroll
      for (int k=0;k<32;k++) c[k&3] = FDOT2(uph(ww1[k]), uph(h2r[k]), c[k&3]);
      sgB[j] = (c[0]+c[1])+(c[2]+c[3]);
    }
    __syncthreads();                               // #1

    // ---- Phase B: cell updates (both layers in parallel lanes)
    if (t < SEQT && j < HID) {
      float gi=sgA[j], gf=sgA[HID+j], gg=sgA[2*HID+j], go=sgA[3*HID+j];
      cst = sigm(gf)*cst + sigm(gi)*tanh_fast(gg);
      float h1 = sigm(go)*tanh_fast(cst);
      ((ushort*)sh1u)[j] = hbits(h1);
    } else if (t >= 1 && j >= HID && j < 2*HID) {
      int u = j - HID;
      float gi=sgB[u], gf=sgB[HID+u], gg=sgB[2*HID+u], go=sgB[3*HID+u];
      cst = sigm(gf)*cst + sigm(gi)*tanh_fast(gg);
      float h2 = sigm(go)*tanh_fast(cst);
      ((ushort*)sh2u)[u] = hbits(h2);
      erow[(size_t)(t-1)*HID + u] = f2b(h2);
    }
    __syncthreads();                               // #2
  }
}

// ---------------- fusion MLP + outputs ----------------
__global__ __launch_bounds__(256) void fuse_kernel(const ushort* __restrict__ envb,
                                                   const float* __restrict__ ws,
                                                   const int* __restrict__ day_ids,
                                                   const void* __restrict__ rawv,
                                                   void* __restrict__ outv,
                                                   const int* __restrict__ flagp,
                                                   int b0, int nb) {
  const int flag = *flagp;
  const int eloc = blockIdx.x*256 + threadIdx.x;
  const int bloc = eloc >> 11;
  const int b = b0 + bloc;
  const size_t ge = (size_t)b*SEQT + (eloc & 2047);

  int day = day_ids[b];
  day = day < 0 ? 0 : (day > 365 ? 365 : day);
  float hl[8];
#pragma unroll
  for (int i=0;i<8;i++) hl[i] = ws[O_TRAJ + day*8 + i];
  float rawD = ws[O_HB];
#pragma unroll
  for (int i=0;i<8;i++) rawD += hl[i]*ws[O_HW+i];
  const float Dv = sigm(rawD);

  float z[HID];
  {
    const uint4* ev = (const uint4*)(envb + (size_t)eloc*HID);
#pragma unroll
    for (int q=0;q<8;q++){
      uint4 u = ev[q];
      z[8*q+0]=blo(u.x); z[8*q+1]=bhi(u.x);
      z[8*q+2]=blo(u.y); z[8*q+3]=bhi(u.y);
      z[8*q+4]=blo(u.z); z[8*q+5]=bhi(u.z);
      z[8*q+6]=blo(u.w); z[8*q+7]=bhi(u.w);
    }
  }
  float G, Tc;
  if (flag) {
    float2 fr = ((const float2*)rawv)[ge*2];
    G = fr.x; Tc = fr.y;
  } else {
    uint gr = ((const uint*)rawv)[ge*2];
    G = blo(gr); Tc = bhi(gr);
  }
  const float Ip = G*9.0f*(1.0f + 0.0005f*(Tc-0.5f));

  float f1[FH];
#pragma unroll
  for (int jj=0;jj<FH;jj++){
    const float* wr = ws + O_FW1 + jj*73;
    float a = ws[O_FB1+jj];
#pragma unroll
    for (int k=0;k<HID;k++) a += wr[k]*z[k];
#pragma unroll
    for (int i=0;i<8;i++) a += wr[HID+i]*hl[i];
    a += wr[72]*Ip;
    f1[jj] = fmaxf(a,0.0f);
  }
  float f2[FH];
#pragma unroll
  for (int jj=0;jj<FH;jj++){
    const float* wr = ws + O_FW2 + jj*FH;
    float a = ws[O_FB2+jj];
#pragma unroll
    for (int k=0;k<FH;k++) a += wr[k]*f1[k];
    f2[jj] = fmaxf(a,0.0f);
  }
  float racc = ws[O_RB2];
#pragma unroll
  for (int mm=0;mm<32;mm++){
    const float* wr = ws + O_RW1 + mm*FH;
    float a = ws[O_RB1+mm];
#pragma unroll
    for (int k=0;k<FH;k++) a += wr[k]*f2[k];
    racc += ws[O_RW2+mm]*fmaxf(a,0.0f);
  }
  const float Ib = Dv*Ip;
  const float Ipred = Ib + racc;

  if (flag) {
    float* o = (float*)outv;
    o[ge] = Ipred; o[NTOT+ge] = Ip; o[(size_t)2*NTOT+ge] = Ib;
    o[(size_t)3*NTOT+ge] = Dv; o[(size_t)4*NTOT+ge] = racc;
    float4* hp = (float4*)(o + (size_t)5*NTOT + ge*8);
    hp[0] = make_float4(hl[0],hl[1],hl[2],hl[3]);
    hp[1] = make_float4(hl[4],hl[5],hl[6],hl[7]);
  } else {
    ushort* o = (ushort*)outv;
    o[ge] = f2b(Ipred); o[NTOT+ge] = f2b(Ip); o[(size_t)2*NTOT+ge] = f2b(Ib);
    o[(size_t)3*NTOT+ge] = f2b(Dv); o[(size_t)4*NTOT+ge] = f2b(racc);
    uint4 hsv;
    hsv.x = (uint)f2b(hl[0]) | ((uint)f2b(hl[1])<<16);
    hsv.y = (uint)f2b(hl[2]) | ((uint)f2b(hl[3])<<16);
    hsv.z = (uint)f2b(hl[4]) | ((uint)f2b(hl[5])<<16);
    hsv.w = (uint)f2b(hl[6]) | ((uint)f2b(hl[7])<<16);
    *((uint4*)(o + (size_t)5*NTOT + ge*8)) = hsv;
  }
}

// ---------------- launch ----------------
extern "C" void kernel_launch(void* const* d_in, const int* in_sizes, int n_in,
                              void* d_out, int out_size, void* d_ws, size_t ws_size,
                              hipStream_t stream) {
  (void)in_sizes; (void)out_size;
  float* wsf = (float*)d_ws;
  int* flagp = (int*)((char*)d_ws + O_FLAG_BYTE);
  ushort* env = (ushort*)((char*)d_ws + ENV_BYTE_OFF);
  Ptrs pa;
  for (int i=0;i<28;i++) pa.p[i] = (i<n_in) ? d_in[i] : d_in[0];

  int S = 1;
  while (S < 128) {
    size_t need = (size_t)ENV_BYTE_OFF + (size_t)(BATCH/S)*SEQT*HID*2;
    if (need <= ws_size) break;
    S <<= 1;
  }
  const int nb = BATCH / S;

  detect_kernel<<<1, 64, 0, stream>>>((const uint*)d_in[0], flagp);
  prep_kernel<<<128, 256, 0, stream>>>(pa, wsf, flagp);
  for (int s=0; s<S; s++) {
    lstm_ode_kernel<<<nb+1, 256, 0, stream>>>(d_in[0], wsf, env, flagp,
                                              s*nb, (s==0)?1:0, nb);
    fuse_kernel<<<nb*(SEQT/256), 256, 0, stream>>>(env, wsf, (const int*)d_in[1],
                                                   d_in[2], d_out, flagp, s*nb, nb);
  }
}